// Round 1
// baseline (114.402 us; speedup 1.0000x reference)
//
#include <hip/hip_runtime.h>
#include <hip/hip_bf16.h>

// SeqOuterProductMean on MI355X.
// Factorization: T[j,p,d] = sum_f s2[j,f]*w3[p,d*32+f]  (GEMM2: M=384,N=4096,K=32)
//                pair[i, j*128+p] = sum_d s1[i,d]*T[j*128+p, d] + b3[p]  (GEMM3: M=384,N=49152,K=32)
// w3 flat [p][d*32+f] == [(p*32+d)][f] row-major -> GEMM2's B with no permute.
// GEMM2 output [384,4096] row-major == GEMM3's B [49152,32] row-major.
// K=32 => one v_mfma_f32_16x16x32_bf16 per 16x16 output tile; A/B frags are
// single 16B/lane loads (m=lane&15, k=quad*8+j layouts; C/D col=lane&15,
// row=quad*4+reg per verified gfx950 mapping).

typedef __attribute__((ext_vector_type(8))) short short8;   // 8 x bf16
typedef __attribute__((ext_vector_type(4))) float f32x4;

static __device__ __forceinline__ short f2bf(float f) {
    unsigned u = __float_as_uint(f);
    unsigned r = u + 0x7fffu + ((u >> 16) & 1u);   // round-to-nearest-even
    return (short)(r >> 16);
}

static __device__ __forceinline__ void store_out(float* D, size_t idx, float v) { D[idx] = v; }
static __device__ __forceinline__ void store_out(short* D, size_t idx, float v) { D[idx] = f2bf(v); }

// ---------------------------------------------------------------------------
// K0: cast w3 (131072 floats) to bf16
// ---------------------------------------------------------------------------
__global__ __launch_bounds__(256) void cast_bf16_kernel(const float* __restrict__ in,
                                                        short* __restrict__ out, int n) {
    int i = blockIdx.x * 256 + threadIdx.x;
    if (i < n) out[i] = f2bf(in[i]);
}

// ---------------------------------------------------------------------------
// K1: LayerNorm + both H=32 projections. One block per sequence row.
// ---------------------------------------------------------------------------
__global__ __launch_bounds__(256) void ln_proj_kernel(
    const float* __restrict__ seq, const float* __restrict__ gamma,
    const float* __restrict__ beta, const float* __restrict__ w1,
    const float* __restrict__ b1, const float* __restrict__ w2,
    const float* __restrict__ b2, short* __restrict__ s1, short* __restrict__ s2) {
    const int row = blockIdx.x;
    const int t = threadIdx.x;
    const int wv = t >> 6;      // wave 0..3
    const int ln = t & 63;      // lane 0..63

    __shared__ float wsum[4];
    __shared__ float xln[256];
    __shared__ float part[4][64];

    float v = seq[row * 256 + t];

    // mean
    float s = v;
    #pragma unroll
    for (int off = 32; off > 0; off >>= 1) s += __shfl_down(s, off);
    if (ln == 0) wsum[wv] = s;
    __syncthreads();
    float mean = (wsum[0] + wsum[1] + wsum[2] + wsum[3]) * (1.0f / 256.0f);

    // variance
    float c = v - mean;
    float cs = c * c;
    #pragma unroll
    for (int off = 32; off > 0; off >>= 1) cs += __shfl_down(cs, off);
    __syncthreads();            // everyone done reading wsum (mean)
    if (ln == 0) wsum[wv] = cs;
    __syncthreads();
    float var = (wsum[0] + wsum[1] + wsum[2] + wsum[3]) * (1.0f / 256.0f);

    float xn = c * rsqrtf(var + 1e-5f) * gamma[t] + beta[t];
    xln[t] = xn;
    __syncthreads();

    // 64 outputs (s1: 0..31, s2: 32..63); 4 waves each cover 64 of the 256 dims.
    const float* w = (ln < 32) ? (w1 + ln * 256) : (w2 + (ln - 32) * 256);
    const float* xs = &xln[wv * 64];
    const float* wp = w + wv * 64;
    float p = 0.0f;
    #pragma unroll 8
    for (int i = 0; i < 64; ++i) p += xs[i] * wp[i];
    part[wv][ln] = p;
    __syncthreads();

    if (t < 64) {
        float r = part[0][t] + part[1][t] + part[2][t] + part[3][t];
        if (t < 32) { r += b1[t];      s1[row * 32 + t]        = f2bf(r); }
        else        { r += b2[t - 32]; s2[row * 32 + (t - 32)] = f2bf(r); }
    }
}

// ---------------------------------------------------------------------------
// K=32 skinny GEMM: D[M,N] = A[M,32] * B[N,32]^T (+ bias[n&127]).
// Block = 4 waves; each wave owns one 16-wide N column (block covers 64 cols),
// holds its B fragment in registers, loops over M tiles (M split by gridDim.y).
// ---------------------------------------------------------------------------
template <typename OutT, bool BIAS>
__global__ __launch_bounds__(256, 4) void gemm_k32_kernel(
    const short* __restrict__ A, const short* __restrict__ B,
    OutT* __restrict__ D, const float* __restrict__ bias, int M, int N) {
    const int lane = threadIdx.x & 63;
    const int wave = threadIdx.x >> 6;
    const int l15  = lane & 15;
    const int quad = lane >> 4;
    const int k0   = quad * 8;
    const int n    = blockIdx.x * 64 + wave * 16 + l15;

    short8 bfrag = *reinterpret_cast<const short8*>(B + (size_t)n * 32 + k0);
    float bv = 0.0f;
    if (BIAS) bv = bias[n & 127];

    const int mchunk = M / gridDim.y;
    const int mbeg = blockIdx.y * mchunk;
    const int mend = mbeg + mchunk;

    const short* aptr = A + (size_t)(mbeg + l15) * 32 + k0;
    size_t dbase = (size_t)(mbeg + quad * 4) * N + n;
    const size_t dstep = (size_t)16 * N;

    for (int m0 = mbeg; m0 < mend; m0 += 16) {
        short8 afrag = *reinterpret_cast<const short8*>(aptr);
        f32x4 acc = {0.0f, 0.0f, 0.0f, 0.0f};
        acc = __builtin_amdgcn_mfma_f32_16x16x32_bf16(afrag, bfrag, acc, 0, 0, 0);
        #pragma unroll
        for (int r = 0; r < 4; ++r)
            store_out(D, dbase + (size_t)r * N, acc[r] + bv);
        aptr += 16 * 32;
        dbase += dstep;
    }
}

// ---------------------------------------------------------------------------
extern "C" void kernel_launch(void* const* d_in, const int* in_sizes, int n_in,
                              void* d_out, int out_size, void* d_ws, size_t ws_size,
                              hipStream_t stream) {
    const float* seq   = (const float*)d_in[0];
    const float* gamma = (const float*)d_in[1];
    const float* beta  = (const float*)d_in[2];
    const float* w1    = (const float*)d_in[3];
    const float* b1    = (const float*)d_in[4];
    const float* w2    = (const float*)d_in[5];
    const float* b2    = (const float*)d_in[6];
    const float* w3    = (const float*)d_in[7];
    const float* b3    = (const float*)d_in[8];
    float* out = (float*)d_out;

    const int L = 384, H = 32, P = 128;
    const int N2 = P * H;        // 4096
    const int N3 = L * P;        // 49152

    char* ws = (char*)d_ws;
    short* s1  = (short*)(ws);                        // 384*32*2   = 24576
    short* s2  = (short*)(ws + 24576);                // 24576
    short* w3c = (short*)(ws + 49152);                // 131072*2   = 262144
    short* T   = (short*)(ws + 311296);               // 384*4096*2 = 3145728
    // total ~3.46 MB of d_ws

    // K0: cast w3 -> bf16 (independent of K1)
    cast_bf16_kernel<<<(P * H * H + 255) / 256, 256, 0, stream>>>(w3, w3c, P * H * H);

    // K1: LayerNorm + s1/s2 projections
    ln_proj_kernel<<<L, 256, 0, stream>>>(seq, gamma, beta, w1, b1, w2, b2, s1, s2);

    // K2: T[j, p*32+d] = sum_f s2[j,f] * w3c[(p*32+d), f]   (bf16 out)
    gemm_k32_kernel<short, false><<<dim3(N2 / 64, 4), 256, 0, stream>>>(
        s2, w3c, T, nullptr, L, N2);

    // K3: pair[i, j*128+p] = sum_d s1[i,d] * T[(j*128+p), d] + b3[p]  (fp32 out)
    gemm_k32_kernel<float, true><<<dim3(N3 / 64, 2), 256, 0, stream>>>(
        s1, T, out, b3, L, N3);
}